// Round 12
// baseline (130.807 us; speedup 1.0000x reference)
//
#include <hip/hip_runtime.h>
#include <hip/hip_bf16.h>
#include <float.h>

#define B_ 64
#define C_ 512
#define Q_ 64
#define D_ 256

typedef _Float16 f16x8 __attribute__((ext_vector_type(8)));
typedef float f32x4 __attribute__((ext_vector_type(4)));

union U4H8 { uint4 u; f16x8 h; };
union UH2 { _Float16 h[2]; uint32_t u; };

__device__ __forceinline__ uint32_t packh2(float a, float b) {
  UH2 v; v.h[0] = (_Float16)a; v.h[1] = (_Float16)b; return v.u;
}

__device__ __forceinline__ float wred_sum(float v) {
#pragma unroll
  for (int off = 32; off > 0; off >>= 1) v += __shfl_xor(v, off, 64);
  return v;
}
__device__ __forceinline__ float wred_max(float v) {
#pragma unroll
  for (int off = 32; off > 0; off >>= 1) v = fmaxf(v, __shfl_xor(v, off, 64));
  return v;
}

// K1 (fallback only): out[row] = dot(src[row, 0:256], wgt[0:256])
__global__ __launch_bounds__(256) void k_rowdot(const float* __restrict__ src,
                                                const float* __restrict__ wgt,
                                                float* __restrict__ out, int nrows) {
  int wv = threadIdx.x >> 6, ln = threadIdx.x & 63;
  int row = blockIdx.x * 4 + wv;
  if (row >= nrows) return;
  float4 s4 = *(const float4*)(src + (size_t)row * D_ + 4 * ln);
  float4 w4 = *(const float4*)(wgt + 4 * ln);
  float p = s4.x * w4.x + s4.y * w4.y + s4.z * w4.z + s4.w * w4.w;
  p = wred_sum(p);
  if (ln == 0) out[row] = p;
}

// K0: prepack question into f16 LDS-images (qraw + qT layouts, XOR swizzle
// baked in) for linear global_load_lds staging in k_main; computes qwq;
// zeroes the per-batch sync counters for k_tail (graph-replay safe).
__global__ __launch_bounds__(512) void k_prepack(const float* __restrict__ qst,
                                                 const float* __restrict__ w,
                                                 uint32_t* __restrict__ qraw_img,
                                                 uint32_t* __restrict__ qT_img,
                                                 float* __restrict__ qwq,
                                                 unsigned int* __restrict__ cnt) {
  const int b = blockIdx.x;
  const int t = threadIdx.x;
  if (t == 0) cnt[b] = 0u;          // reset k_tail sync counter each call
  const float* qb = qst + (size_t)b * Q_ * D_;
  // pass 1: qraw image — byte layout: q*512 + phys*16 + (jp&3)*4,
  // phys = (ch&~7)|((ch&7)^(q&7)), ch = jp>>2. 16*512 = 8192 u32 per b.
#pragma unroll
  for (int it = 0; it < 16; ++it) {
    int idx = it * 512 + t;
    int q = idx >> 7, jp = idx & 127;
    float2 v = *(const float2*)(qb + q * D_ + 2 * jp);
    int ch = jp >> 2;
    int phys = (ch & ~7) | ((ch & 7) ^ (q & 7));
    qraw_img[(size_t)b * 8192 + q * 128 + phys * 4 + (jp & 3)] = packh2(v.x, v.y);
  }
  if (t < 256) {
    // pass 2a: qT image row d = t — byte layout: d*128 + ((qc^(d&7))<<4) + (q&7)*2
    int d = t;
    uint32_t* dst = qT_img + (size_t)b * 8192 + d * 32;
#pragma unroll
    for (int qc = 0; qc < 8; ++qc) {
      uint32_t tmp[4];
#pragma unroll
      for (int e = 0; e < 4; ++e) {
        int q0 = qc * 8 + e * 2;
        tmp[e] = packh2(qb[q0 * D_ + d], qb[(q0 + 1) * D_ + d]);
      }
      int pc = qc ^ (d & 7);
      *(uint4*)(dst + pc * 4) = uint4{tmp[0], tmp[1], tmp[2], tmp[3]};
    }
  } else {
    // pass 2b: qwq[q] = dot(question[q], w_q); 4 lanes per q
    int q = (t - 256) >> 2, sl = t & 3;
    float p = 0.f;
#pragma unroll
    for (int i = 0; i < 16; ++i) {
      float4 v = *(const float4*)(qb + q * D_ + sl * 64 + i * 4);
      float4 ww = *(const float4*)(w + D_ + sl * 64 + i * 4);
      p += v.x * ww.x + v.y * ww.y + v.z * ww.z + v.w * ww.w;
    }
    p += __shfl_xor(p, 1, 64);
    p += __shfl_xor(p, 2, 64);
    if (sl == 0) qwq[b * Q_ + q] = p;
  }
}

// K2 (MFMA): r6-proven structure. IMG=1: stage qraw/qT linearly from the
// prepacked images via global_load_lds width-16. IMG=0: r9 fallback staging.
// LDS = 32K(qraw) + 32K(qT) + 8K(P) + .5K = ~74 KB -> 2 blocks/CU.
template<int IMG>
__global__ __launch_bounds__(256, 2) void k_main(
    const float* __restrict__ ctx, const float* __restrict__ qst,
    const int* __restrict__ qmask, const float* __restrict__ w,
    const float* __restrict__ qwq_g,
    const uint32_t* __restrict__ qraw_img, const uint32_t* __restrict__ qT_img,
    float* __restrict__ g, float* __restrict__ simmax_g) {
  __shared__ __align__(16) ushort qraw[Q_ * D_];
  __shared__ __align__(16) ushort qT[D_ * Q_];
  __shared__ __align__(16) ushort pbuf[4][16 * Q_];
  __shared__ float qwq_l[Q_];
  __shared__ int   qml_l[Q_];

  const int bid = blockIdx.x;
  const int b = bid & 63;           // XCD-swizzle: same-b blocks share an XCD
  const int c0 = (bid >> 6) * 64;
  const int t = threadIdx.x;
  const int wv = t >> 6, ln = t & 63;
  const int lc = ln & 15;
  const int lg = ln >> 4;
  const int c0w = c0 + wv * 16;

  // ---- issue LINEAR image->LDS staging FIRST (latency hides under bfrag work) ----
  if constexpr (IMG) {
    const uint32_t* qr_src = qraw_img + (size_t)b * 8192;
    const uint32_t* qt_src = qT_img + (size_t)b * 8192;
#pragma unroll
    for (int i = 0; i < 8; ++i)
      __builtin_amdgcn_global_load_lds(
          (const __attribute__((address_space(1))) uint32_t*)(qr_src + i * 1024 + t * 4),
          (__attribute__((address_space(3))) uint32_t*)((uint32_t*)qraw + i * 1024 + t * 4),
          16, 0, 0);
#pragma unroll
    for (int i = 0; i < 8; ++i)
      __builtin_amdgcn_global_load_lds(
          (const __attribute__((address_space(1))) uint32_t*)(qt_src + i * 1024 + t * 4),
          (__attribute__((address_space(3))) uint32_t*)((uint32_t*)qT + i * 1024 + t * 4),
          16, 0, 0);
  }

  // ---- B-frags: this wave's 16 ctx rows * w_m (f16), fused g0-copy + fp32 cwc dot ----
  f16x8 bfrag[8];
  float cwc_p = 0.f;
  const float* crow = ctx + ((size_t)b * C_ + c0w + lc) * D_;
  float* grow0 = g + ((size_t)b * C_ + c0w + lc) * (4 * D_);
#pragma unroll
  for (int kk = 0; kk < 8; ++kk) {
    int kb = kk * 32 + lg * 8;
    float4 cv0 = *(const float4*)(crow + kb);
    float4 cv1 = *(const float4*)(crow + kb + 4);
    float4 wc0 = *(const float4*)(w + kb);
    float4 wc1 = *(const float4*)(w + kb + 4);
    float4 wm0 = *(const float4*)(w + 2 * D_ + kb);
    float4 wm1 = *(const float4*)(w + 2 * D_ + kb + 4);
    cwc_p += cv0.x * wc0.x + cv0.y * wc0.y + cv0.z * wc0.z + cv0.w * wc0.w
           + cv1.x * wc1.x + cv1.y * wc1.y + cv1.z * wc1.z + cv1.w * wc1.w;
    bfrag[kk][0] = (_Float16)(cv0.x * wm0.x);
    bfrag[kk][1] = (_Float16)(cv0.y * wm0.y);
    bfrag[kk][2] = (_Float16)(cv0.z * wm0.z);
    bfrag[kk][3] = (_Float16)(cv0.w * wm0.w);
    bfrag[kk][4] = (_Float16)(cv1.x * wm1.x);
    bfrag[kk][5] = (_Float16)(cv1.y * wm1.y);
    bfrag[kk][6] = (_Float16)(cv1.z * wm1.z);
    bfrag[kk][7] = (_Float16)(cv1.w * wm1.w);
    *(float4*)(grow0 + kb) = cv0;          // g[0:D] = ctx exact copy
    *(float4*)(grow0 + kb + 4) = cv1;
  }
  float cwc = cwc_p;
  cwc += __shfl_xor(cwc, 16, 64);
  cwc += __shfl_xor(cwc, 32, 64);

  if constexpr (!IMG) {
    const float* qb = qst + (size_t)b * Q_ * D_;
#pragma unroll 4
    for (int it = 0; it < 32; ++it) {
      int idx = it * 256 + t;
      int q = idx >> 7, jp = idx & 127;
      float2 v = *(const float2*)(qb + q * D_ + 2 * jp);
      int ch = jp >> 2;
      int phys = (ch & ~7) | ((ch & 7) ^ (q & 7));
      *(uint32_t*)((char*)qraw + q * 512 + phys * 16 + (jp & 3) * 4) = packh2(v.x, v.y);
    }
#pragma unroll 4
    for (int it = 0; it < 32; ++it) {
      int q = t & 63;
      int jp = (t >> 6) + 4 * it;
      float2 v = *(const float2*)(qb + q * D_ + 2 * jp);
      int d0 = 2 * jp, d1 = d0 + 1;
      UH2 h0; h0.h[0] = (_Float16)v.x;
      UH2 h1; h1.h[0] = (_Float16)v.y;
      *(ushort*)((char*)qT + d0 * 128 + (((q >> 3) ^ (d0 & 7)) << 4) + (q & 7) * 2) = (ushort)(h0.u & 0xffff);
      *(ushort*)((char*)qT + d1 * 128 + (((q >> 3) ^ (d1 & 7)) << 4) + (q & 7) * 2) = (ushort)(h1.u & 0xffff);
    }
  }
  if (t < Q_) { qwq_l[t] = qwq_g[b * Q_ + t]; qml_l[t] = qmask[b * Q_ + t]; }
  __syncthreads();   // drains global_load_lds (vmcnt) + LDS writes

  // ---- simT[q, c] via MFMA: A = question rows (qraw), B = (ctx*wm) cols ----
  f32x4 sacc[4];
#pragma unroll
  for (int tq = 0; tq < 4; ++tq) sacc[tq] = f32x4{0.f, 0.f, 0.f, 0.f};
#pragma unroll
  for (int tq = 0; tq < 4; ++tq) {
    int q = 16 * tq + lc;
#pragma unroll
    for (int kk = 0; kk < 8; ++kk) {
      int ch = lg + 4 * kk;
      int phys = (ch & ~7) | ((ch & 7) ^ (q & 7));
      U4H8 a; a.u = *(const uint4*)((const char*)qraw + q * 512 + phys * 16);
      sacc[tq] = __builtin_amdgcn_mfma_f32_16x16x32_f16(a.h, bfrag[kk], sacc[tq], 0, 0, 0);
    }
  }

  // ---- softmax over q (16 in-lane vals + xor16/xor32), P -> pbuf ----
  float vals[4][4];
  float rmax = -FLT_MAX;
#pragma unroll
  for (int tq = 0; tq < 4; ++tq) {
    float4 qw4 = *(const float4*)(qwq_l + 16 * tq + 4 * lg);
#pragma unroll
    for (int r = 0; r < 4; ++r) {
      float qv = (r == 0) ? qw4.x : (r == 1) ? qw4.y : (r == 2) ? qw4.z : qw4.w;
      vals[tq][r] = sacc[tq][r] + cwc + qv;
      rmax = fmaxf(rmax, vals[tq][r]);
    }
  }
  rmax = fmaxf(rmax, __shfl_xor(rmax, 16, 64));
  rmax = fmaxf(rmax, __shfl_xor(rmax, 32, 64));
  if (ln < 16) simmax_g[b * C_ + c0w + lc] = rmax;   // unmasked max (ref semantics)

  float mmax = -FLT_MAX;
#pragma unroll
  for (int tq = 0; tq < 4; ++tq) {
    int4 qm4 = *(const int4*)(qml_l + 16 * tq + 4 * lg);
#pragma unroll
    for (int r = 0; r < 4; ++r) {
      int m = (r == 0) ? qm4.x : (r == 1) ? qm4.y : (r == 2) ? qm4.z : qm4.w;
      vals[tq][r] = m ? vals[tq][r] : -FLT_MAX;
      mmax = fmaxf(mmax, vals[tq][r]);
    }
  }
  mmax = fmaxf(mmax, __shfl_xor(mmax, 16, 64));
  mmax = fmaxf(mmax, __shfl_xor(mmax, 32, 64));
  float esum = 0.f;
#pragma unroll
  for (int tq = 0; tq < 4; ++tq)
#pragma unroll
    for (int r = 0; r < 4; ++r) {
      vals[tq][r] = __expf(vals[tq][r] - mmax);      // masked -> exp(-huge) = 0
      esum += vals[tq][r];
    }
  esum += __shfl_xor(esum, 16, 64);
  esum += __shfl_xor(esum, 32, 64);
  float inv = 1.f / esum;
#pragma unroll
  for (int tq = 0; tq < 4; ++tq) {
    uint32_t p01 = packh2(vals[tq][0] * inv, vals[tq][1] * inv);
    uint32_t p23 = packh2(vals[tq][2] * inv, vals[tq][3] * inv);
    int qb4 = 16 * tq + 4 * lg;
    int phys = ((qb4 >> 3) ^ (lc & 7));
    char* dst = (char*)pbuf[wv] + lc * 128 + phys * 16 + (qb4 & 7) * 2;
    *(uint2*)dst = uint2{p01, p23};
  }
  // pbuf[wv] is wave-private: no block barrier needed

  // ---- c2qT[d, c] via MFMA: A = qT rows (d), B = P cols (c) ----
  f16x8 pfragB[2];
#pragma unroll
  for (int ks = 0; ks < 2; ++ks) {
    int phys = (lg + 4 * ks) ^ (lc & 7);
    U4H8 a; a.u = *(const uint4*)((const char*)pbuf[wv] + lc * 128 + phys * 16);
    pfragB[ks] = a.h;
  }
  const float* crow2 = ctx + ((size_t)b * C_ + c0w + lc) * D_;
  float* grow = g + ((size_t)b * C_ + c0w + lc) * (4 * D_);
#pragma unroll 4
  for (int dt = 0; dt < 16; ++dt) {
    f32x4 acc = f32x4{0.f, 0.f, 0.f, 0.f};
#pragma unroll
    for (int ks = 0; ks < 2; ++ks) {
      int d = dt * 16 + lc;
      int phys = (lg + 4 * ks) ^ (d & 7);
      U4H8 aq; aq.u = *(const uint4*)((const char*)qT + d * 128 + phys * 16);
      acc = __builtin_amdgcn_mfma_f32_16x16x32_f16(aq.h, pfragB[ks], acc, 0, 0, 0);
    }
    int dcol = dt * 16 + 4 * lg;
    float4 cvv = *(const float4*)(crow2 + dcol);
    float4 c2qv{acc[0], acc[1], acc[2], acc[3]};
    *(float4*)(grow + D_ + dcol) = c2qv;                       // g[D:2D] = c2q
    float4 p2{cvv.x * c2qv.x, cvv.y * c2qv.y, cvv.z * c2qv.z, cvv.w * c2qv.w};
    *(float4*)(grow + 2 * D_ + dcol) = p2;                     // g[2D:3D] = ctx*c2q
  }
}

// K3 (fused tail): per-batch masked softmax + partial q2c, device-scope
// inter-block sync (8 blocks per batch), then q2c reduce + g3 stream over the
// SAME 64 ctx rows (L1/L2-hot re-read). Deterministic: fixed k-order sum.
__global__ __launch_bounds__(256) void k_tail(const float* __restrict__ ctx,
                                              const float* __restrict__ simmax,
                                              const int* __restrict__ cmask,
                                              float* __restrict__ part,
                                              unsigned int* __restrict__ cnt,
                                              float* __restrict__ g) {
  int b = blockIdx.x, ch = blockIdx.y, t = threadIdx.x;
  int wv = t >> 6, ln = t & 63;
  __shared__ float bls[C_];
  __shared__ float sred[4];
  __shared__ float ssum_s[4];
  __shared__ float q2c_l[D_];
  float v0 = simmax[b * C_ + t], v1 = simmax[b * C_ + 256 + t];
  if (!cmask[b * C_ + t]) v0 = -FLT_MAX;
  if (!cmask[b * C_ + 256 + t]) v1 = -FLT_MAX;
  float mx = wred_max(fmaxf(v0, v1));
  if (ln == 0) sred[wv] = mx;
  __syncthreads();
  float bm = fmaxf(fmaxf(sred[0], sred[1]), fmaxf(sred[2], sred[3]));
  float e0 = __expf(v0 - bm), e1 = __expf(v1 - bm);
  float ps = wred_sum(e0 + e1);
  if (ln == 0) ssum_s[wv] = ps;
  __syncthreads();
  float bs = ssum_s[0] + ssum_s[1] + ssum_s[2] + ssum_s[3];
  float invbs = 1.f / bs;
  bls[t] = e0 * invbs;
  bls[256 + t] = e1 * invbs;
  __syncthreads();
  float acc = 0.f;
  int cbeg = ch * 64;
#pragma unroll 4
  for (int c = cbeg; c < cbeg + 64; ++c)
    acc += bls[c] * ctx[((size_t)b * C_ + c) * D_ + t];
  part[((size_t)b * 8 + ch) * D_ + t] = acc;
  // ---- release own part, signal, wait for all 8 chunks of this batch ----
  __threadfence();          // device-scope release of part stores (per thread)
  __syncthreads();
  if (t == 0) {
    atomicAdd(&cnt[b], 1u);
    while (atomicAdd(&cnt[b], 0u) < 8u) __builtin_amdgcn_s_sleep(2);
  }
  __syncthreads();
  __threadfence();          // device-scope acquire before reading other parts
  // ---- q2c = sum of 8 partials (fixed order) -> LDS ----
  float s = 0.f;
#pragma unroll
  for (int k = 0; k < 8; ++k) s += part[((size_t)b * 8 + k) * D_ + t];
  q2c_l[t] = s;
  __syncthreads();
  // ---- g3 = ctx * q2c for this block's 64 rows (ctx cache-hot) ----
  int d4 = t & 63;
  int ro = t >> 6;
  float4 qv = *(const float4*)(q2c_l + 4 * d4);
#pragma unroll 4
  for (int it = 0; it < 16; ++it) {
    int c = cbeg + it * 4 + ro;
    float4 cv = *(const float4*)(ctx + ((size_t)b * C_ + c) * D_ + 4 * d4);
    float4 o{cv.x * qv.x, cv.y * qv.y, cv.z * qv.z, cv.w * qv.w};
    *(float4*)(g + ((size_t)b * C_ + c) * (4 * D_) + 3 * D_ + 4 * d4) = o;
  }
}

// Fallback tail (ws too small): r11's separate kernels
__global__ __launch_bounds__(256) void k_q2c_bs(const float* __restrict__ ctx,
                                                const float* __restrict__ simmax,
                                                const int* __restrict__ cmask,
                                                float* __restrict__ part) {
  int b = blockIdx.x, ch = blockIdx.y, t = threadIdx.x;
  int wv = t >> 6, ln = t & 63;
  __shared__ float bls[C_];
  __shared__ float sred[4];
  __shared__ float ssum[4];
  float v0 = simmax[b * C_ + t], v1 = simmax[b * C_ + 256 + t];
  if (!cmask[b * C_ + t]) v0 = -FLT_MAX;
  if (!cmask[b * C_ + 256 + t]) v1 = -FLT_MAX;
  float mx = wred_max(fmaxf(v0, v1));
  if (ln == 0) sred[wv] = mx;
  __syncthreads();
  float bm = fmaxf(fmaxf(sred[0], sred[1]), fmaxf(sred[2], sred[3]));
  float e0 = __expf(v0 - bm), e1 = __expf(v1 - bm);
  float ps = wred_sum(e0 + e1);
  if (ln == 0) ssum[wv] = ps;
  __syncthreads();
  float bs = ssum[0] + ssum[1] + ssum[2] + ssum[3];
  float invbs = 1.f / bs;
  bls[t] = e0 * invbs;
  bls[256 + t] = e1 * invbs;
  __syncthreads();
  float acc = 0.f;
  int cbeg = ch * 64;
#pragma unroll 4
  for (int c = cbeg; c < cbeg + 64; ++c)
    acc += bls[c] * ctx[((size_t)b * C_ + c) * D_ + t];
  part[((size_t)b * 8 + ch) * D_ + t] = acc;
}

__global__ __launch_bounds__(256) void k_g3q(const float* __restrict__ ctx,
                                             const float* __restrict__ part,
                                             float* __restrict__ g) {
  int b = blockIdx.x, ch = blockIdx.y, t = threadIdx.x;
  __shared__ float q2c_l[D_];
  float s = 0.f;
#pragma unroll
  for (int k = 0; k < 8; ++k) s += part[((size_t)b * 8 + k) * D_ + t];
  q2c_l[t] = s;
  __syncthreads();
  int d4 = t & 63;
  int ro = t >> 6;
  float4 qv = *(const float4*)(q2c_l + 4 * d4);
#pragma unroll 4
  for (int it = 0; it < 16; ++it) {
    int c = ch * 64 + it * 4 + ro;
    float4 cv = *(const float4*)(ctx + ((size_t)b * C_ + c) * D_ + 4 * d4);
    float4 o{cv.x * qv.x, cv.y * qv.y, cv.z * qv.z, cv.w * qv.w};
    *(float4*)(g + ((size_t)b * C_ + c) * (4 * D_) + 3 * D_ + 4 * d4) = o;
  }
}

extern "C" void kernel_launch(void* const* d_in, const int* in_sizes, int n_in,
                              void* d_out, int out_size, void* d_ws, size_t ws_size,
                              hipStream_t stream) {
  const float* ctx   = (const float*)d_in[0];
  const float* qst   = (const float*)d_in[1];
  const int*   cmask = (const int*)d_in[2];
  const int*   qmask = (const int*)d_in[3];
  const float* w     = (const float*)d_in[4];
  float* g  = (float*)d_out;
  float* ws = (float*)d_ws;

  float*        qwq      = ws;             // B*Q   = 4096 floats
  float*        simmax   = ws + 4096;      // B*C   = 32768
  float*        part     = ws + 36864;     // B*8*D = 131072
  uint32_t*     qraw_img = (uint32_t*)(ws + 167936);   // 524288 u32 (2 MB)
  uint32_t*     qT_img   = (uint32_t*)(ws + 692224);   // 524288 u32 (2 MB)
  unsigned int* cnt      = (unsigned int*)(ws + 1216512);  // 64 u32
  const size_t need_bytes = (size_t)(1216512 + 64) * 4;    // ~4.87 MB

  if (ws_size >= need_bytes) {
    k_prepack<<<dim3(B_), 512, 0, stream>>>(qst, w, qraw_img, qT_img, qwq, cnt);
    k_main<1><<<dim3(512), 256, 0, stream>>>(ctx, qst, qmask, w, qwq,
                                             qraw_img, qT_img, g, simmax);
    k_tail<<<dim3(B_, 8), 256, 0, stream>>>(ctx, simmax, cmask, part, cnt, g);
  } else {
    k_rowdot<<<dim3(B_ * Q_ / 4), 256, 0, stream>>>(qst, w + D_, qwq, B_ * Q_);
    k_main<0><<<dim3(512), 256, 0, stream>>>(ctx, qst, qmask, w, qwq,
                                             qraw_img, qT_img, g, simmax);
    k_q2c_bs<<<dim3(B_, 8), 256, 0, stream>>>(ctx, simmax, cmask, part);
    k_g3q<<<dim3(B_, 8), 256, 0, stream>>>(ctx, part, g);
  }
}

// Round 13
// 65.283 us; speedup vs baseline: 2.0037x; 2.0037x over previous
//
#include <hip/hip_runtime.h>
#include <hip/hip_bf16.h>
#include <float.h>

#define B_ 64
#define C_ 512
#define Q_ 64
#define D_ 256

typedef _Float16 f16x8 __attribute__((ext_vector_type(8)));
typedef float f32x4 __attribute__((ext_vector_type(4)));

union U4H8 { uint4 u; f16x8 h; };
union UH2 { _Float16 h[2]; uint32_t u; };

__device__ __forceinline__ uint32_t packh2(float a, float b) {
  UH2 v; v.h[0] = (_Float16)a; v.h[1] = (_Float16)b; return v.u;
}

__device__ __forceinline__ float wred_sum(float v) {
#pragma unroll
  for (int off = 32; off > 0; off >>= 1) v += __shfl_xor(v, off, 64);
  return v;
}
__device__ __forceinline__ float wred_max(float v) {
#pragma unroll
  for (int off = 32; off > 0; off >>= 1) v = fmaxf(v, __shfl_xor(v, off, 64));
  return v;
}

// K1 (fallback only): out[row] = dot(src[row, 0:256], wgt[0:256])
__global__ __launch_bounds__(256) void k_rowdot(const float* __restrict__ src,
                                                const float* __restrict__ wgt,
                                                float* __restrict__ out, int nrows) {
  int wv = threadIdx.x >> 6, ln = threadIdx.x & 63;
  int row = blockIdx.x * 4 + wv;
  if (row >= nrows) return;
  float4 s4 = *(const float4*)(src + (size_t)row * D_ + 4 * ln);
  float4 w4 = *(const float4*)(wgt + 4 * ln);
  float p = s4.x * w4.x + s4.y * w4.y + s4.z * w4.z + s4.w * w4.w;
  p = wred_sum(p);
  if (ln == 0) out[row] = p;
}

// K0: prepack question into f16 images (qraw + qT layouts, XOR swizzle baked
// in). qT_img is staged to LDS by k_main; qraw_img is read DIRECTLY (L2-hot)
// as simT A-frags. Also computes qwq. grid 64, 512 thr.
__global__ __launch_bounds__(512) void k_prepack(const float* __restrict__ qst,
                                                 const float* __restrict__ w,
                                                 uint32_t* __restrict__ qraw_img,
                                                 uint32_t* __restrict__ qT_img,
                                                 float* __restrict__ qwq) {
  const int b = blockIdx.x;
  const int t = threadIdx.x;
  const float* qb = qst + (size_t)b * Q_ * D_;
  // pass 1: qraw image — byte layout: q*512 + phys*16 + (jp&3)*4,
  // phys = (ch&~7)|((ch&7)^(q&7)), ch = jp>>2. 16*512 = 8192 u32 per b.
#pragma unroll
  for (int it = 0; it < 16; ++it) {
    int idx = it * 512 + t;
    int q = idx >> 7, jp = idx & 127;
    float2 v = *(const float2*)(qb + q * D_ + 2 * jp);
    int ch = jp >> 2;
    int phys = (ch & ~7) | ((ch & 7) ^ (q & 7));
    qraw_img[(size_t)b * 8192 + q * 128 + phys * 4 + (jp & 3)] = packh2(v.x, v.y);
  }
  if (t < 256) {
    // pass 2a: qT image row d = t — byte layout: d*128 + ((qc^(d&7))<<4) + (q&7)*2
    int d = t;
    uint32_t* dst = qT_img + (size_t)b * 8192 + d * 32;
#pragma unroll
    for (int qc = 0; qc < 8; ++qc) {
      uint32_t tmp[4];
#pragma unroll
      for (int e = 0; e < 4; ++e) {
        int q0 = qc * 8 + e * 2;
        tmp[e] = packh2(qb[q0 * D_ + d], qb[(q0 + 1) * D_ + d]);
      }
      int pc = qc ^ (d & 7);
      *(uint4*)(dst + pc * 4) = uint4{tmp[0], tmp[1], tmp[2], tmp[3]};
    }
  } else {
    // pass 2b: qwq[q] = dot(question[q], w_q); 4 lanes per q
    int q = (t - 256) >> 2, sl = t & 3;
    float p = 0.f;
#pragma unroll
    for (int i = 0; i < 16; ++i) {
      float4 v = *(const float4*)(qb + q * D_ + sl * 64 + i * 4);
      float4 ww = *(const float4*)(w + D_ + sl * 64 + i * 4);
      p += v.x * ww.x + v.y * ww.y + v.z * ww.z + v.w * ww.w;
    }
    p += __shfl_xor(p, 1, 64);
    p += __shfl_xor(p, 2, 64);
    if (sl == 0) qwq[b * Q_ + q] = p;
  }
}

// K2 (MFMA): IMG=1: qT staged linearly via global_load_lds; simT A-frags read
// DIRECTLY from qraw_img (L2-hot, per-lane 16B) — qraw LDS deleted.
// LDS = 32K(qT) + 8K(P) + .5K = ~41.5 KB -> 3 blocks/CU (12 waves/CU).
// IMG=0 fallback: r9 in-LDS staging (qraw LDS via template size).
template<int IMG>
__global__ __launch_bounds__(256, 3) void k_main(
    const float* __restrict__ ctx, const float* __restrict__ qst,
    const int* __restrict__ qmask, const float* __restrict__ w,
    const float* __restrict__ qwq_g,
    const uint32_t* __restrict__ qraw_img, const uint32_t* __restrict__ qT_img,
    float* __restrict__ g, float* __restrict__ simmax_g) {
  __shared__ __align__(16) ushort qraw[IMG ? 8 : Q_ * D_];  // dead when IMG=1
  __shared__ __align__(16) ushort qT[D_ * Q_];
  __shared__ __align__(16) ushort pbuf[4][16 * Q_];
  __shared__ float qwq_l[Q_];
  __shared__ int   qml_l[Q_];

  const int bid = blockIdx.x;
  const int b = bid & 63;           // XCD-swizzle: same-b blocks share an XCD
  const int c0 = (bid >> 6) * 64;
  const int t = threadIdx.x;
  const int wv = t >> 6, ln = t & 63;
  const int lc = ln & 15;
  const int lg = ln >> 4;
  const int c0w = c0 + wv * 16;
  const uint32_t* qr_src = qraw_img + (size_t)b * 8192;

  // ---- issue LINEAR qT image->LDS staging FIRST (hides under bfrag work) ----
  if constexpr (IMG) {
    const uint32_t* qt_src = qT_img + (size_t)b * 8192;
#pragma unroll
    for (int i = 0; i < 8; ++i)
      __builtin_amdgcn_global_load_lds(
          (const __attribute__((address_space(1))) uint32_t*)(qt_src + i * 1024 + t * 4),
          (__attribute__((address_space(3))) uint32_t*)((uint32_t*)qT + i * 1024 + t * 4),
          16, 0, 0);
  }

  // ---- B-frags: this wave's 16 ctx rows * w_m (f16), fused g0-copy + fp32 cwc dot ----
  f16x8 bfrag[8];
  float cwc_p = 0.f;
  const float* crow = ctx + ((size_t)b * C_ + c0w + lc) * D_;
  float* grow0 = g + ((size_t)b * C_ + c0w + lc) * (4 * D_);
#pragma unroll
  for (int kk = 0; kk < 8; ++kk) {
    int kb = kk * 32 + lg * 8;
    float4 cv0 = *(const float4*)(crow + kb);
    float4 cv1 = *(const float4*)(crow + kb + 4);
    float4 wc0 = *(const float4*)(w + kb);
    float4 wc1 = *(const float4*)(w + kb + 4);
    float4 wm0 = *(const float4*)(w + 2 * D_ + kb);
    float4 wm1 = *(const float4*)(w + 2 * D_ + kb + 4);
    cwc_p += cv0.x * wc0.x + cv0.y * wc0.y + cv0.z * wc0.z + cv0.w * wc0.w
           + cv1.x * wc1.x + cv1.y * wc1.y + cv1.z * wc1.z + cv1.w * wc1.w;
    bfrag[kk][0] = (_Float16)(cv0.x * wm0.x);
    bfrag[kk][1] = (_Float16)(cv0.y * wm0.y);
    bfrag[kk][2] = (_Float16)(cv0.z * wm0.z);
    bfrag[kk][3] = (_Float16)(cv0.w * wm0.w);
    bfrag[kk][4] = (_Float16)(cv1.x * wm1.x);
    bfrag[kk][5] = (_Float16)(cv1.y * wm1.y);
    bfrag[kk][6] = (_Float16)(cv1.z * wm1.z);
    bfrag[kk][7] = (_Float16)(cv1.w * wm1.w);
    *(float4*)(grow0 + kb) = cv0;          // g[0:D] = ctx exact copy
    *(float4*)(grow0 + kb + 4) = cv1;
  }
  float cwc = cwc_p;
  cwc += __shfl_xor(cwc, 16, 64);
  cwc += __shfl_xor(cwc, 32, 64);

  if constexpr (!IMG) {
    const float* qb = qst + (size_t)b * Q_ * D_;
#pragma unroll 4
    for (int it = 0; it < 32; ++it) {
      int idx = it * 256 + t;
      int q = idx >> 7, jp = idx & 127;
      float2 v = *(const float2*)(qb + q * D_ + 2 * jp);
      int ch = jp >> 2;
      int phys = (ch & ~7) | ((ch & 7) ^ (q & 7));
      *(uint32_t*)((char*)qraw + q * 512 + phys * 16 + (jp & 3) * 4) = packh2(v.x, v.y);
    }
#pragma unroll 4
    for (int it = 0; it < 32; ++it) {
      int q = t & 63;
      int jp = (t >> 6) + 4 * it;
      float2 v = *(const float2*)(qb + q * D_ + 2 * jp);
      int d0 = 2 * jp, d1 = d0 + 1;
      UH2 h0; h0.h[0] = (_Float16)v.x;
      UH2 h1; h1.h[0] = (_Float16)v.y;
      *(ushort*)((char*)qT + d0 * 128 + (((q >> 3) ^ (d0 & 7)) << 4) + (q & 7) * 2) = (ushort)(h0.u & 0xffff);
      *(ushort*)((char*)qT + d1 * 128 + (((q >> 3) ^ (d1 & 7)) << 4) + (q & 7) * 2) = (ushort)(h1.u & 0xffff);
    }
  }
  if (t < Q_) { qwq_l[t] = qwq_g[b * Q_ + t]; qml_l[t] = qmask[b * Q_ + t]; }
  __syncthreads();   // drains global_load_lds (vmcnt) + LDS writes

  // ---- simT[q, c] via MFMA: A = question rows, B = (ctx*wm) cols ----
  // IMG=1: A-frags straight from qraw_img (L2-hot per-lane 16B loads).
  f32x4 sacc[4];
#pragma unroll
  for (int tq = 0; tq < 4; ++tq) sacc[tq] = f32x4{0.f, 0.f, 0.f, 0.f};
#pragma unroll
  for (int tq = 0; tq < 4; ++tq) {
    int q = 16 * tq + lc;
    U4H8 af[8];
#pragma unroll
    for (int kk = 0; kk < 8; ++kk) {
      int ch = lg + 4 * kk;
      int phys = (ch & ~7) | ((ch & 7) ^ (q & 7));
      if constexpr (IMG)
        af[kk].u = *(const uint4*)(qr_src + q * 128 + phys * 4);
      else
        af[kk].u = *(const uint4*)((const char*)qraw + q * 512 + phys * 16);
    }
#pragma unroll
    for (int kk = 0; kk < 8; ++kk)
      sacc[tq] = __builtin_amdgcn_mfma_f32_16x16x32_f16(af[kk].h, bfrag[kk], sacc[tq], 0, 0, 0);
  }

  // ---- softmax over q (16 in-lane vals + xor16/xor32), P -> pbuf ----
  float vals[4][4];
  float rmax = -FLT_MAX;
#pragma unroll
  for (int tq = 0; tq < 4; ++tq) {
    float4 qw4 = *(const float4*)(qwq_l + 16 * tq + 4 * lg);
#pragma unroll
    for (int r = 0; r < 4; ++r) {
      float qv = (r == 0) ? qw4.x : (r == 1) ? qw4.y : (r == 2) ? qw4.z : qw4.w;
      vals[tq][r] = sacc[tq][r] + cwc + qv;
      rmax = fmaxf(rmax, vals[tq][r]);
    }
  }
  rmax = fmaxf(rmax, __shfl_xor(rmax, 16, 64));
  rmax = fmaxf(rmax, __shfl_xor(rmax, 32, 64));
  if (ln < 16) simmax_g[b * C_ + c0w + lc] = rmax;   // unmasked max (ref semantics)

  float mmax = -FLT_MAX;
#pragma unroll
  for (int tq = 0; tq < 4; ++tq) {
    int4 qm4 = *(const int4*)(qml_l + 16 * tq + 4 * lg);
#pragma unroll
    for (int r = 0; r < 4; ++r) {
      int m = (r == 0) ? qm4.x : (r == 1) ? qm4.y : (r == 2) ? qm4.z : qm4.w;
      vals[tq][r] = m ? vals[tq][r] : -FLT_MAX;
      mmax = fmaxf(mmax, vals[tq][r]);
    }
  }
  mmax = fmaxf(mmax, __shfl_xor(mmax, 16, 64));
  mmax = fmaxf(mmax, __shfl_xor(mmax, 32, 64));
  float esum = 0.f;
#pragma unroll
  for (int tq = 0; tq < 4; ++tq)
#pragma unroll
    for (int r = 0; r < 4; ++r) {
      vals[tq][r] = __expf(vals[tq][r] - mmax);      // masked -> exp(-huge) = 0
      esum += vals[tq][r];
    }
  esum += __shfl_xor(esum, 16, 64);
  esum += __shfl_xor(esum, 32, 64);
  float inv = 1.f / esum;
#pragma unroll
  for (int tq = 0; tq < 4; ++tq) {
    uint32_t p01 = packh2(vals[tq][0] * inv, vals[tq][1] * inv);
    uint32_t p23 = packh2(vals[tq][2] * inv, vals[tq][3] * inv);
    int qb4 = 16 * tq + 4 * lg;
    int phys = ((qb4 >> 3) ^ (lc & 7));
    char* dst = (char*)pbuf[wv] + lc * 128 + phys * 16 + (qb4 & 7) * 2;
    *(uint2*)dst = uint2{p01, p23};
  }
  // pbuf[wv] is wave-private: no block barrier needed

  // ---- c2qT[d, c] via MFMA: A = qT rows (d, LDS), B = P cols (c) ----
  f16x8 pfragB[2];
#pragma unroll
  for (int ks = 0; ks < 2; ++ks) {
    int phys = (lg + 4 * ks) ^ (lc & 7);
    U4H8 a; a.u = *(const uint4*)((const char*)pbuf[wv] + lc * 128 + phys * 16);
    pfragB[ks] = a.h;
  }
  const float* crow2 = ctx + ((size_t)b * C_ + c0w + lc) * D_;
  float* grow = g + ((size_t)b * C_ + c0w + lc) * (4 * D_);
#pragma unroll 4
  for (int dt = 0; dt < 16; ++dt) {
    f32x4 acc = f32x4{0.f, 0.f, 0.f, 0.f};
#pragma unroll
    for (int ks = 0; ks < 2; ++ks) {
      int d = dt * 16 + lc;
      int phys = (lg + 4 * ks) ^ (d & 7);
      U4H8 aq; aq.u = *(const uint4*)((const char*)qT + d * 128 + phys * 16);
      acc = __builtin_amdgcn_mfma_f32_16x16x32_f16(aq.h, pfragB[ks], acc, 0, 0, 0);
    }
    int dcol = dt * 16 + 4 * lg;
    float4 cvv = *(const float4*)(crow2 + dcol);
    float4 c2qv{acc[0], acc[1], acc[2], acc[3]};
    *(float4*)(grow + D_ + dcol) = c2qv;                       // g[D:2D] = c2q
    float4 p2{cvv.x * c2qv.x, cvv.y * c2qv.y, cvv.z * c2qv.z, cvv.w * c2qv.w};
    *(float4*)(grow + 2 * D_ + dcol) = p2;                     // g[2D:3D] = ctx*c2q
  }
}

// K3: fused per-batch masked softmax over sim_max + partial q2c
__global__ __launch_bounds__(256) void k_q2c_bs(const float* __restrict__ ctx,
                                                const float* __restrict__ simmax,
                                                const int* __restrict__ cmask,
                                                float* __restrict__ part) {
  int b = blockIdx.x, ch = blockIdx.y, t = threadIdx.x;
  int wv = t >> 6, ln = t & 63;
  __shared__ float bls[C_];
  __shared__ float sred[4];
  __shared__ float ssum[4];
  float v0 = simmax[b * C_ + t], v1 = simmax[b * C_ + 256 + t];
  if (!cmask[b * C_ + t]) v0 = -FLT_MAX;
  if (!cmask[b * C_ + 256 + t]) v1 = -FLT_MAX;
  float mx = wred_max(fmaxf(v0, v1));
  if (ln == 0) sred[wv] = mx;
  __syncthreads();
  float bm = fmaxf(fmaxf(sred[0], sred[1]), fmaxf(sred[2], sred[3]));
  float e0 = __expf(v0 - bm), e1 = __expf(v1 - bm);
  float ps = wred_sum(e0 + e1);
  if (ln == 0) ssum[wv] = ps;
  __syncthreads();
  float bs = ssum[0] + ssum[1] + ssum[2] + ssum[3];
  float invbs = 1.f / bs;
  bls[t] = e0 * invbs;
  bls[256 + t] = e1 * invbs;
  __syncthreads();
  float acc = 0.f;
  int cbeg = ch * 64;
#pragma unroll 4
  for (int c = cbeg; c < cbeg + 64; ++c)
    acc += bls[c] * ctx[((size_t)b * C_ + c) * D_ + t];
  part[((size_t)b * 8 + ch) * D_ + t] = acc;
}

// K4: reduce partials (redundant per block, L2-hot) -> q2c in LDS, then
// stream 64 ctx rows writing g[3D:4D] = ctx * q2c with float4.
__global__ __launch_bounds__(256) void k_g3q(const float* __restrict__ ctx,
                                             const float* __restrict__ part,
                                             float* __restrict__ g) {
  int b = blockIdx.x, ch = blockIdx.y, t = threadIdx.x;
  __shared__ float q2c_l[D_];
  float s = 0.f;
#pragma unroll
  for (int k = 0; k < 8; ++k) s += part[((size_t)b * 8 + k) * D_ + t];
  q2c_l[t] = s;
  __syncthreads();
  int d4 = t & 63;
  int ro = t >> 6;
  float4 qv = *(const float4*)(q2c_l + 4 * d4);
#pragma unroll 4
  for (int it = 0; it < 16; ++it) {
    int c = ch * 64 + it * 4 + ro;
    float4 cv = *(const float4*)(ctx + ((size_t)b * C_ + c) * D_ + 4 * d4);
    float4 o{cv.x * qv.x, cv.y * qv.y, cv.z * qv.z, cv.w * qv.w};
    *(float4*)(g + ((size_t)b * C_ + c) * (4 * D_) + 3 * D_ + 4 * d4) = o;
  }
}

extern "C" void kernel_launch(void* const* d_in, const int* in_sizes, int n_in,
                              void* d_out, int out_size, void* d_ws, size_t ws_size,
                              hipStream_t stream) {
  const float* ctx   = (const float*)d_in[0];
  const float* qst   = (const float*)d_in[1];
  const int*   cmask = (const int*)d_in[2];
  const int*   qmask = (const int*)d_in[3];
  const float* w     = (const float*)d_in[4];
  float* g  = (float*)d_out;
  float* ws = (float*)d_ws;

  float*    qwq      = ws;             // B*Q   = 4096 floats
  float*    simmax   = ws + 4096;      // B*C   = 32768
  float*    part     = ws + 36864;     // B*8*D = 131072
  uint32_t* qraw_img = (uint32_t*)(ws + 167936);   // 524288 u32 (2 MB)
  uint32_t* qT_img   = (uint32_t*)(ws + 692224);   // 524288 u32 (2 MB)
  const size_t need_bytes = (size_t)(692224 + 524288) * 4;   // ~4.64 MB

  if (ws_size >= need_bytes) {
    k_prepack<<<dim3(B_), 512, 0, stream>>>(qst, w, qraw_img, qT_img, qwq);
    k_main<1><<<dim3(512), 256, 0, stream>>>(ctx, qst, qmask, w, qwq,
                                             qraw_img, qT_img, g, simmax);
  } else {
    k_rowdot<<<dim3(B_ * Q_ / 4), 256, 0, stream>>>(qst, w + D_, qwq, B_ * Q_);
    k_main<0><<<dim3(512), 256, 0, stream>>>(ctx, qst, qmask, w, qwq,
                                             qraw_img, qT_img, g, simmax);
  }
  k_q2c_bs<<<dim3(B_, 8), 256, 0, stream>>>(ctx, simmax, cmask, part);
  k_g3q<<<dim3(B_, 8), 256, 0, stream>>>(ctx, part, g);
}

// Round 14
// 61.541 us; speedup vs baseline: 2.1255x; 1.0608x over previous
//
#include <hip/hip_runtime.h>
#include <hip/hip_bf16.h>
#include <float.h>

#define B_ 64
#define C_ 512
#define Q_ 64
#define D_ 256

typedef _Float16 f16x8 __attribute__((ext_vector_type(8)));
typedef float f32x4 __attribute__((ext_vector_type(4)));

union U4H8 { uint4 u; f16x8 h; };
union UH2 { _Float16 h[2]; uint32_t u; };

__device__ __forceinline__ uint32_t packh2(float a, float b) {
  UH2 v; v.h[0] = (_Float16)a; v.h[1] = (_Float16)b; return v.u;
}

__device__ __forceinline__ float wred_sum(float v) {
#pragma unroll
  for (int off = 32; off > 0; off >>= 1) v += __shfl_xor(v, off, 64);
  return v;
}
__device__ __forceinline__ float wred_max(float v) {
#pragma unroll
  for (int off = 32; off > 0; off >>= 1) v = fmaxf(v, __shfl_xor(v, off, 64));
  return v;
}

// K1 (fallback only): out[row] = dot(src[row, 0:256], wgt[0:256])
__global__ __launch_bounds__(256) void k_rowdot(const float* __restrict__ src,
                                                const float* __restrict__ wgt,
                                                float* __restrict__ out, int nrows) {
  int wv = threadIdx.x >> 6, ln = threadIdx.x & 63;
  int row = blockIdx.x * 4 + wv;
  if (row >= nrows) return;
  float4 s4 = *(const float4*)(src + (size_t)row * D_ + 4 * ln);
  float4 w4 = *(const float4*)(wgt + 4 * ln);
  float p = s4.x * w4.x + s4.y * w4.y + s4.z * w4.z + s4.w * w4.w;
  p = wred_sum(p);
  if (ln == 0) out[row] = p;
}

// K0: prepack question into f16 images (qraw + qT layouts, XOR swizzle baked
// in) for linear global_load_lds staging in k_main; computes qwq.
// Parallelized: grid (B, 4) x 256 thr = 256 blocks (4x r11's parallelism).
__global__ __launch_bounds__(256) void k_prepack(const float* __restrict__ qst,
                                                 const float* __restrict__ w,
                                                 uint32_t* __restrict__ qraw_img,
                                                 uint32_t* __restrict__ qT_img,
                                                 float* __restrict__ qwq) {
  const int b = blockIdx.x;
  const int sub = blockIdx.y;      // 0..3
  const int t = threadIdx.x;
  const float* qb = qst + (size_t)b * Q_ * D_;
  // pass 1: qraw image — byte layout: q*512 + phys*16 + (jp&3)*4,
  // phys = (ch&~7)|((ch&7)^(q&7)), ch = jp>>2. This sub: idx in [sub*2048, +2048).
#pragma unroll
  for (int it = 0; it < 8; ++it) {
    int idx = sub * 2048 + it * 256 + t;
    int q = idx >> 7, jp = idx & 127;
    float2 v = *(const float2*)(qb + q * D_ + 2 * jp);
    int ch = jp >> 2;
    int phys = (ch & ~7) | ((ch & 7) ^ (q & 7));
    qraw_img[(size_t)b * 8192 + q * 128 + phys * 4 + (jp & 3)] = packh2(v.x, v.y);
  }
  // pass 2a: qT image — d = sub*64 + (t>>2); this thread does 2 qc-chunks.
  {
    int d = sub * 64 + (t >> 2);
    uint32_t* dst = qT_img + (size_t)b * 8192 + d * 32;
#pragma unroll
    for (int k = 0; k < 2; ++k) {
      int qc = (t & 3) * 2 + k;
      uint32_t tmp[4];
#pragma unroll
      for (int e = 0; e < 4; ++e) {
        int q0 = qc * 8 + e * 2;
        tmp[e] = packh2(qb[q0 * D_ + d], qb[(q0 + 1) * D_ + d]);
      }
      int pc = qc ^ (d & 7);
      *(uint4*)(dst + pc * 4) = uint4{tmp[0], tmp[1], tmp[2], tmp[3]};
    }
  }
  // pass 2b (sub 0 only): qwq[q] = dot(question[q], w_q); 4 lanes per q
  if (sub == 0) {
    int q = t >> 2, sl = t & 3;
    float p = 0.f;
#pragma unroll
    for (int i = 0; i < 16; ++i) {
      float4 v = *(const float4*)(qb + q * D_ + sl * 64 + i * 4);
      float4 ww = *(const float4*)(w + D_ + sl * 64 + i * 4);
      p += v.x * ww.x + v.y * ww.y + v.z * ww.z + v.w * ww.w;
    }
    p += __shfl_xor(p, 1, 64);
    p += __shfl_xor(p, 2, 64);
    if (sl == 0) qwq[b * Q_ + q] = p;
  }
}

// K2 (MFMA): r6-proven structure. IMG=1: stage qraw/qT linearly from the
// prepacked images via global_load_lds width-16. IMG=0: r9 fallback staging.
// LDS = 32K(qraw) + 32K(qT) + 8K(P) + .5K = ~74 KB -> 2 blocks/CU.
template<int IMG>
__global__ __launch_bounds__(256, 2) void k_main(
    const float* __restrict__ ctx, const float* __restrict__ qst,
    const int* __restrict__ qmask, const float* __restrict__ w,
    const float* __restrict__ qwq_g,
    const uint32_t* __restrict__ qraw_img, const uint32_t* __restrict__ qT_img,
    float* __restrict__ g, float* __restrict__ simmax_g) {
  __shared__ __align__(16) ushort qraw[Q_ * D_];
  __shared__ __align__(16) ushort qT[D_ * Q_];
  __shared__ __align__(16) ushort pbuf[4][16 * Q_];
  __shared__ float qwq_l[Q_];
  __shared__ int   qml_l[Q_];

  const int bid = blockIdx.x;
  const int b = bid & 63;           // XCD-swizzle: same-b blocks share an XCD
  const int c0 = (bid >> 6) * 64;
  const int t = threadIdx.x;
  const int wv = t >> 6, ln = t & 63;
  const int lc = ln & 15;
  const int lg = ln >> 4;
  const int c0w = c0 + wv * 16;

  // ---- issue LINEAR image->LDS staging FIRST (latency hides under bfrag work) ----
  if constexpr (IMG) {
    const uint32_t* qr_src = qraw_img + (size_t)b * 8192;
    const uint32_t* qt_src = qT_img + (size_t)b * 8192;
#pragma unroll
    for (int i = 0; i < 8; ++i)
      __builtin_amdgcn_global_load_lds(
          (const __attribute__((address_space(1))) uint32_t*)(qr_src + i * 1024 + t * 4),
          (__attribute__((address_space(3))) uint32_t*)((uint32_t*)qraw + i * 1024 + t * 4),
          16, 0, 0);
#pragma unroll
    for (int i = 0; i < 8; ++i)
      __builtin_amdgcn_global_load_lds(
          (const __attribute__((address_space(1))) uint32_t*)(qt_src + i * 1024 + t * 4),
          (__attribute__((address_space(3))) uint32_t*)((uint32_t*)qT + i * 1024 + t * 4),
          16, 0, 0);
  }

  // ---- B-frags: this wave's 16 ctx rows * w_m (f16), fused g0-copy + fp32 cwc dot ----
  f16x8 bfrag[8];
  float cwc_p = 0.f;
  const float* crow = ctx + ((size_t)b * C_ + c0w + lc) * D_;
  float* grow0 = g + ((size_t)b * C_ + c0w + lc) * (4 * D_);
#pragma unroll
  for (int kk = 0; kk < 8; ++kk) {
    int kb = kk * 32 + lg * 8;
    float4 cv0 = *(const float4*)(crow + kb);
    float4 cv1 = *(const float4*)(crow + kb + 4);
    float4 wc0 = *(const float4*)(w + kb);
    float4 wc1 = *(const float4*)(w + kb + 4);
    float4 wm0 = *(const float4*)(w + 2 * D_ + kb);
    float4 wm1 = *(const float4*)(w + 2 * D_ + kb + 4);
    cwc_p += cv0.x * wc0.x + cv0.y * wc0.y + cv0.z * wc0.z + cv0.w * wc0.w
           + cv1.x * wc1.x + cv1.y * wc1.y + cv1.z * wc1.z + cv1.w * wc1.w;
    bfrag[kk][0] = (_Float16)(cv0.x * wm0.x);
    bfrag[kk][1] = (_Float16)(cv0.y * wm0.y);
    bfrag[kk][2] = (_Float16)(cv0.z * wm0.z);
    bfrag[kk][3] = (_Float16)(cv0.w * wm0.w);
    bfrag[kk][4] = (_Float16)(cv1.x * wm1.x);
    bfrag[kk][5] = (_Float16)(cv1.y * wm1.y);
    bfrag[kk][6] = (_Float16)(cv1.z * wm1.z);
    bfrag[kk][7] = (_Float16)(cv1.w * wm1.w);
    *(float4*)(grow0 + kb) = cv0;          // g[0:D] = ctx exact copy
    *(float4*)(grow0 + kb + 4) = cv1;
  }
  float cwc = cwc_p;
  cwc += __shfl_xor(cwc, 16, 64);
  cwc += __shfl_xor(cwc, 32, 64);

  if constexpr (!IMG) {
    const float* qb = qst + (size_t)b * Q_ * D_;
#pragma unroll 4
    for (int it = 0; it < 32; ++it) {
      int idx = it * 256 + t;
      int q = idx >> 7, jp = idx & 127;
      float2 v = *(const float2*)(qb + q * D_ + 2 * jp);
      int ch = jp >> 2;
      int phys = (ch & ~7) | ((ch & 7) ^ (q & 7));
      *(uint32_t*)((char*)qraw + q * 512 + phys * 16 + (jp & 3) * 4) = packh2(v.x, v.y);
    }
#pragma unroll 4
    for (int it = 0; it < 32; ++it) {
      int q = t & 63;
      int jp = (t >> 6) + 4 * it;
      float2 v = *(const float2*)(qb + q * D_ + 2 * jp);
      int d0 = 2 * jp, d1 = d0 + 1;
      UH2 h0; h0.h[0] = (_Float16)v.x;
      UH2 h1; h1.h[0] = (_Float16)v.y;
      *(ushort*)((char*)qT + d0 * 128 + (((q >> 3) ^ (d0 & 7)) << 4) + (q & 7) * 2) = (ushort)(h0.u & 0xffff);
      *(ushort*)((char*)qT + d1 * 128 + (((q >> 3) ^ (d1 & 7)) << 4) + (q & 7) * 2) = (ushort)(h1.u & 0xffff);
    }
  }
  if (t < Q_) { qwq_l[t] = qwq_g[b * Q_ + t]; qml_l[t] = qmask[b * Q_ + t]; }
  __syncthreads();   // drains global_load_lds (vmcnt) + LDS writes

  // ---- simT[q, c] via MFMA: A = question rows (qraw), B = (ctx*wm) cols ----
  f32x4 sacc[4];
#pragma unroll
  for (int tq = 0; tq < 4; ++tq) sacc[tq] = f32x4{0.f, 0.f, 0.f, 0.f};
#pragma unroll
  for (int tq = 0; tq < 4; ++tq) {
    int q = 16 * tq + lc;
#pragma unroll
    for (int kk = 0; kk < 8; ++kk) {
      int ch = lg + 4 * kk;
      int phys = (ch & ~7) | ((ch & 7) ^ (q & 7));
      U4H8 a; a.u = *(const uint4*)((const char*)qraw + q * 512 + phys * 16);
      sacc[tq] = __builtin_amdgcn_mfma_f32_16x16x32_f16(a.h, bfrag[kk], sacc[tq], 0, 0, 0);
    }
  }

  // ---- softmax over q (16 in-lane vals + xor16/xor32), P -> pbuf ----
  float vals[4][4];
  float rmax = -FLT_MAX;
#pragma unroll
  for (int tq = 0; tq < 4; ++tq) {
    float4 qw4 = *(const float4*)(qwq_l + 16 * tq + 4 * lg);
#pragma unroll
    for (int r = 0; r < 4; ++r) {
      float qv = (r == 0) ? qw4.x : (r == 1) ? qw4.y : (r == 2) ? qw4.z : qw4.w;
      vals[tq][r] = sacc[tq][r] + cwc + qv;
      rmax = fmaxf(rmax, vals[tq][r]);
    }
  }
  rmax = fmaxf(rmax, __shfl_xor(rmax, 16, 64));
  rmax = fmaxf(rmax, __shfl_xor(rmax, 32, 64));
  if (ln < 16) simmax_g[b * C_ + c0w + lc] = rmax;   // unmasked max (ref semantics)

  float mmax = -FLT_MAX;
#pragma unroll
  for (int tq = 0; tq < 4; ++tq) {
    int4 qm4 = *(const int4*)(qml_l + 16 * tq + 4 * lg);
#pragma unroll
    for (int r = 0; r < 4; ++r) {
      int m = (r == 0) ? qm4.x : (r == 1) ? qm4.y : (r == 2) ? qm4.z : qm4.w;
      vals[tq][r] = m ? vals[tq][r] : -FLT_MAX;
      mmax = fmaxf(mmax, vals[tq][r]);
    }
  }
  mmax = fmaxf(mmax, __shfl_xor(mmax, 16, 64));
  mmax = fmaxf(mmax, __shfl_xor(mmax, 32, 64));
  float esum = 0.f;
#pragma unroll
  for (int tq = 0; tq < 4; ++tq)
#pragma unroll
    for (int r = 0; r < 4; ++r) {
      vals[tq][r] = __expf(vals[tq][r] - mmax);      // masked -> exp(-huge) = 0
      esum += vals[tq][r];
    }
  esum += __shfl_xor(esum, 16, 64);
  esum += __shfl_xor(esum, 32, 64);
  float inv = 1.f / esum;
#pragma unroll
  for (int tq = 0; tq < 4; ++tq) {
    uint32_t p01 = packh2(vals[tq][0] * inv, vals[tq][1] * inv);
    uint32_t p23 = packh2(vals[tq][2] * inv, vals[tq][3] * inv);
    int qb4 = 16 * tq + 4 * lg;
    int phys = ((qb4 >> 3) ^ (lc & 7));
    char* dst = (char*)pbuf[wv] + lc * 128 + phys * 16 + (qb4 & 7) * 2;
    *(uint2*)dst = uint2{p01, p23};
  }
  // pbuf[wv] is wave-private: no block barrier needed

  // ---- c2qT[d, c] via MFMA: A = qT rows (d), B = P cols (c) ----
  f16x8 pfragB[2];
#pragma unroll
  for (int ks = 0; ks < 2; ++ks) {
    int phys = (lg + 4 * ks) ^ (lc & 7);
    U4H8 a; a.u = *(const uint4*)((const char*)pbuf[wv] + lc * 128 + phys * 16);
    pfragB[ks] = a.h;
  }
  const float* crow2 = ctx + ((size_t)b * C_ + c0w + lc) * D_;
  float* grow = g + ((size_t)b * C_ + c0w + lc) * (4 * D_);
#pragma unroll 4
  for (int dt = 0; dt < 16; ++dt) {
    f32x4 acc = f32x4{0.f, 0.f, 0.f, 0.f};
#pragma unroll
    for (int ks = 0; ks < 2; ++ks) {
      int d = dt * 16 + lc;
      int phys = (lg + 4 * ks) ^ (d & 7);
      U4H8 aq; aq.u = *(const uint4*)((const char*)qT + d * 128 + phys * 16);
      acc = __builtin_amdgcn_mfma_f32_16x16x32_f16(aq.h, pfragB[ks], acc, 0, 0, 0);
    }
    int dcol = dt * 16 + 4 * lg;
    float4 cvv = *(const float4*)(crow2 + dcol);
    float4 c2qv{acc[0], acc[1], acc[2], acc[3]};
    *(float4*)(grow + D_ + dcol) = c2qv;                       // g[D:2D] = c2q
    float4 p2{cvv.x * c2qv.x, cvv.y * c2qv.y, cvv.z * c2qv.z, cvv.w * c2qv.w};
    *(float4*)(grow + 2 * D_ + dcol) = p2;                     // g[2D:3D] = ctx*c2q
  }
}

// K3: fused per-batch masked softmax over sim_max + partial q2c
__global__ __launch_bounds__(256) void k_q2c_bs(const float* __restrict__ ctx,
                                                const float* __restrict__ simmax,
                                                const int* __restrict__ cmask,
                                                float* __restrict__ part) {
  int b = blockIdx.x, ch = blockIdx.y, t = threadIdx.x;
  int wv = t >> 6, ln = t & 63;
  __shared__ float bls[C_];
  __shared__ float sred[4];
  __shared__ float ssum[4];
  float v0 = simmax[b * C_ + t], v1 = simmax[b * C_ + 256 + t];
  if (!cmask[b * C_ + t]) v0 = -FLT_MAX;
  if (!cmask[b * C_ + 256 + t]) v1 = -FLT_MAX;
  float mx = wred_max(fmaxf(v0, v1));
  if (ln == 0) sred[wv] = mx;
  __syncthreads();
  float bm = fmaxf(fmaxf(sred[0], sred[1]), fmaxf(sred[2], sred[3]));
  float e0 = __expf(v0 - bm), e1 = __expf(v1 - bm);
  float ps = wred_sum(e0 + e1);
  if (ln == 0) ssum[wv] = ps;
  __syncthreads();
  float bs = ssum[0] + ssum[1] + ssum[2] + ssum[3];
  float invbs = 1.f / bs;
  bls[t] = e0 * invbs;
  bls[256 + t] = e1 * invbs;
  __syncthreads();
  float acc = 0.f;
  int cbeg = ch * 64;
#pragma unroll 4
  for (int c = cbeg; c < cbeg + 64; ++c)
    acc += bls[c] * ctx[((size_t)b * C_ + c) * D_ + t];
  part[((size_t)b * 8 + ch) * D_ + t] = acc;
}

// K4: reduce partials (redundant per block, L2-hot) -> q2c in LDS, then
// stream 64 ctx rows writing g[3D:4D] = ctx * q2c with float4.
__global__ __launch_bounds__(256) void k_g3q(const float* __restrict__ ctx,
                                             const float* __restrict__ part,
                                             float* __restrict__ g) {
  int b = blockIdx.x, ch = blockIdx.y, t = threadIdx.x;
  __shared__ float q2c_l[D_];
  float s = 0.f;
#pragma unroll
  for (int k = 0; k < 8; ++k) s += part[((size_t)b * 8 + k) * D_ + t];
  q2c_l[t] = s;
  __syncthreads();
  int d4 = t & 63;
  int ro = t >> 6;
  float4 qv = *(const float4*)(q2c_l + 4 * d4);
#pragma unroll 4
  for (int it = 0; it < 16; ++it) {
    int c = ch * 64 + it * 4 + ro;
    float4 cv = *(const float4*)(ctx + ((size_t)b * C_ + c) * D_ + 4 * d4);
    float4 o{cv.x * qv.x, cv.y * qv.y, cv.z * qv.z, cv.w * qv.w};
    *(float4*)(g + ((size_t)b * C_ + c) * (4 * D_) + 3 * D_ + 4 * d4) = o;
  }
}

extern "C" void kernel_launch(void* const* d_in, const int* in_sizes, int n_in,
                              void* d_out, int out_size, void* d_ws, size_t ws_size,
                              hipStream_t stream) {
  const float* ctx   = (const float*)d_in[0];
  const float* qst   = (const float*)d_in[1];
  const int*   cmask = (const int*)d_in[2];
  const int*   qmask = (const int*)d_in[3];
  const float* w     = (const float*)d_in[4];
  float* g  = (float*)d_out;
  float* ws = (float*)d_ws;

  float*    qwq      = ws;             // B*Q   = 4096 floats
  float*    simmax   = ws + 4096;      // B*C   = 32768
  float*    part     = ws + 36864;     // B*8*D = 131072
  uint32_t* qraw_img = (uint32_t*)(ws + 167936);   // 524288 u32 (2 MB)
  uint32_t* qT_img   = (uint32_t*)(ws + 692224);   // 524288 u32 (2 MB)
  const size_t need_bytes = (size_t)(692224 + 524288) * 4;   // ~4.64 MB

  if (ws_size >= need_bytes) {
    k_prepack<<<dim3(B_, 4), 256, 0, stream>>>(qst, w, qraw_img, qT_img, qwq);
    k_main<1><<<dim3(512), 256, 0, stream>>>(ctx, qst, qmask, w, qwq,
                                             qraw_img, qT_img, g, simmax);
  } else {
    k_rowdot<<<dim3(B_ * Q_ / 4), 256, 0, stream>>>(qst, w + D_, qwq, B_ * Q_);
    k_main<0><<<dim3(512), 256, 0, stream>>>(ctx, qst, qmask, w, qwq,
                                             qraw_img, qT_img, g, simmax);
  }
  k_q2c_bs<<<dim3(B_, 8), 256, 0, stream>>>(ctx, simmax, cmask, part);
  k_g3q<<<dim3(B_, 8), 256, 0, stream>>>(ctx, part, g);
}